// Round 2
// baseline (73499.420 us; speedup 1.0000x reference)
//
#include <hip/hip_runtime.h>
#include <stdint.h>
#include <math.h>

namespace {

constexpr int B = 256, L = 256, F = 38, H = 512, D = 512, Z = 16, NF = 20;
constexpr float LOG2PI_F = 1.8378770664093453f;
constexpr int LBZ = L * B * Z;      // 1048576
constexpr int HALF = LBZ / 2;       // 524288
constexpr int HB = H * B;           // 131072
constexpr int DB = D * B;           // 131072
constexpr int ZB = Z * B;           // 4096
constexpr int LFB = L * F * B;      // 2490368
constexpr int GRIDN = 512;          // persistent grid: 2 blocks/CU on 256 CUs

// ---------------- math helpers ----------------

__device__ __forceinline__ float sigmoidf_(float x) {
  return 1.0f / (1.0f + expf(-x));
}
__device__ __forceinline__ float softplusf_(float x) {
  return fmaxf(x, 0.0f) + log1pf(expf(-fabsf(x)));
}

__device__ __forceinline__ void waveReduceAtomicAdd(float* dst, float v, int tid) {
  #pragma unroll
  for (int off = 32; off > 0; off >>= 1) v += __shfl_down(v, off, 64);
  if ((tid & 63) == 0) atomicAdd(dst, v);
}

// ---------------- grid barrier (device-scope, sense-reversing) -------------
// bar[0] = arrival count, bar[1] = generation. All blocks resident (grid=512,
// capacity 2 blocks/CU by launch_bounds, LDS 32KB -> 5/CU). Spin is RELAXED
// agent-scope loads (no per-iteration cache ops); one __threadfence release
// on arrival, one acquire on exit.
__device__ __forceinline__ void grid_sync_(uint32_t* bar) {
  __syncthreads();
  if (threadIdx.x == 0) {
    __threadfence();  // release: flush this block's phase writes to device scope
    uint32_t g = __hip_atomic_load(&bar[1], __ATOMIC_RELAXED, __HIP_MEMORY_SCOPE_AGENT);
    uint32_t a = __hip_atomic_fetch_add(&bar[0], 1u, __ATOMIC_RELAXED, __HIP_MEMORY_SCOPE_AGENT);
    if (a == (uint32_t)(GRIDN - 1)) {
      __hip_atomic_store(&bar[0], 0u, __ATOMIC_RELAXED, __HIP_MEMORY_SCOPE_AGENT);
      __threadfence();  // order count reset before generation flip
      __hip_atomic_fetch_add(&bar[1], 1u, __ATOMIC_RELAXED, __HIP_MEMORY_SCOPE_AGENT);
    } else {
      while (__hip_atomic_load(&bar[1], __ATOMIC_RELAXED, __HIP_MEMORY_SCOPE_AGENT) == g)
        __builtin_amdgcn_s_sleep(2);
    }
    __threadfence();  // acquire: invalidate stale cache before next phase reads
  }
  __syncthreads();
}

// ---------------- threefry2x32 (JAX-compatible) ----------------

__host__ __device__ inline uint32_t rotl32_(uint32_t x, int d) {
  return (x << d) | (x >> (32 - d));
}

__host__ __device__ inline void threefry2x32_(uint32_t k0, uint32_t k1,
                                              uint32_t x0, uint32_t x1,
                                              uint32_t& o0, uint32_t& o1) {
  const uint32_t ks2 = k0 ^ k1 ^ 0x1BD11BDAu;
  uint32_t v0 = x0 + k0;
  uint32_t v1 = x1 + k1;
#define TF_RND(r) { v0 += v1; v1 = rotl32_(v1, r); v1 ^= v0; }
  TF_RND(13) TF_RND(15) TF_RND(26) TF_RND(6)
  v0 += k1;  v1 += ks2 + 1u;
  TF_RND(17) TF_RND(29) TF_RND(16) TF_RND(24)
  v0 += ks2; v1 += k0 + 2u;
  TF_RND(13) TF_RND(15) TF_RND(26) TF_RND(6)
  v0 += k0;  v1 += k1 + 3u;
  TF_RND(17) TF_RND(29) TF_RND(16) TF_RND(24)
  v0 += k1;  v1 += ks2 + 4u;
  TF_RND(13) TF_RND(15) TF_RND(26) TF_RND(6)
  v0 += ks2; v1 += k0 + 5u;
#undef TF_RND
  o0 = v0; o1 = v1;
}

__device__ __forceinline__ float erfinv_f_(float x) {
  float w = -log1pf(-x * x);
  float p;
  if (w < 5.0f) {
    w -= 2.5f;
    p = 2.81022636e-08f;
    p = fmaf(p, w, 3.43273939e-07f);
    p = fmaf(p, w, -3.5233877e-06f);
    p = fmaf(p, w, -4.39150654e-06f);
    p = fmaf(p, w, 0.00021858087f);
    p = fmaf(p, w, -0.00125372503f);
    p = fmaf(p, w, -0.00417768164f);
    p = fmaf(p, w, 0.246640727f);
    p = fmaf(p, w, 1.50140941f);
  } else {
    w = sqrtf(w) - 3.0f;
    p = -0.000200214257f;
    p = fmaf(p, w, 0.000100950558f);
    p = fmaf(p, w, 0.00134934322f);
    p = fmaf(p, w, -0.00367342844f);
    p = fmaf(p, w, 0.00573950773f);
    p = fmaf(p, w, -0.0076224613f);
    p = fmaf(p, w, 0.00943887047f);
    p = fmaf(p, w, 1.00167406f);
    p = fmaf(p, w, 2.83297682f);
  }
  return p * x;
}

__device__ __forceinline__ float bits_to_normal_(uint32_t bits) {
  uint32_t m = (bits >> 9) | 0x3f800000u;
  float f = __uint_as_float(m) - 1.0f;
  float u = f * 2.0f + (-0.99999994f);
  u = fmaxf(-0.99999994f, u);
  return 1.41421356f * erfinv_f_(u);
}

// planar flows for one batch column (per-lane), returns logdet; zv updated in place
__device__ __forceinline__ float flows_dev(float zv[Z], const float* __restrict__ pu,
                                           const float* __restrict__ pw,
                                           const float* __restrict__ pb) {
  float ld = 0.0f;
  for (int f = 0; f < NF; ++f) {
    const float* w = pw + f * Z;
    const float* u = pu + f * Z;
    float wn2 = 0.0f, wu = 0.0f;
    #pragma unroll
    for (int i = 0; i < Z; ++i) { wn2 = fmaf(w[i], w[i], wn2); wu = fmaf(w[i], u[i], wu); }
    float coef = (softplusf_(wu) - 1.0f - wu) / wn2;
    float a_in = pb[f];
    #pragma unroll
    for (int i = 0; i < Z; ++i) a_in = fmaf(zv[i], w[i], a_in);
    float a = tanhf(a_in);
    float uw = 0.0f;
    #pragma unroll
    for (int i = 0; i < Z; ++i) {
      float uh = fmaf(coef, w[i], u[i]);
      uw = fmaf(uh, w[i], uw);
      zv[i] = fmaf(uh, a, zv[i]);
    }
    ld += logf(fabsf(1.0f + (1.0f - a * a) * uw) + 1e-12f);
  }
  return ld;
}

// ---------------- small utility kernels ----------------

__global__ __launch_bounds__(256) void k_transpose_x(const float* __restrict__ x,
                                                     float* __restrict__ xT) {
  int idx = blockIdx.x * blockDim.x + threadIdx.x;  // over B*L*F
  int f = idx % F;
  int t = (idx / F) % L;
  int b = idx / (F * L);
  xT[(t * F + f) * B + b] = x[idx];
}

__global__ __launch_bounds__(256) void k_noise(float* __restrict__ eps_z,
                                               float* __restrict__ kld_acc,
                                               uint32_t kz0, uint32_t kz1,
                                               uint32_t kp0, uint32_t kp1) {
  int i = blockIdx.x * blockDim.x + threadIdx.x;  // [0, HALF)
  uint32_t a0, a1, b0, b1;
  threefry2x32_(kz0, kz1, (uint32_t)i, (uint32_t)(i + HALF), a0, a1);
  float ez0 = bits_to_normal_(a0);
  float ez1 = bits_to_normal_(a1);
  eps_z[i] = ez0;
  eps_z[i + HALF] = ez1;
  threefry2x32_(kp0, kp1, (uint32_t)i, (uint32_t)(i + HALF), b0, b1);
  float ep0 = bits_to_normal_(b0);
  float ep1 = bits_to_normal_(b1);
  float local = -0.5f * (ez0 * ez0 + ez1 * ez1) + 0.5f * (ep0 * ep0 + ep1 * ep1);
  waveReduceAtomicAdd(kld_acc, local, threadIdx.x);
}

__global__ void k_finalize(const float* __restrict__ acc, float* __restrict__ out) {
  out[(size_t)B * L * F] = acc[1];      // recon
  out[(size_t)B * L * F + 1] = acc[0];  // kld
}

// ---------------- weight composition (once per launch) ----------------
// Wc[r][k] = sum_j A[r][j] * W2[j][k]; bc[r] = sum_j A[r][j]*b2[j] + bA[r]
__global__ __launch_bounds__(256) void k_compose(
    const float* __restrict__ A, const float* __restrict__ bA,
    const float* __restrict__ W2, const float* __restrict__ b2,
    float* __restrict__ Wc, float* __restrict__ bc) {
  const int r = blockIdx.x;
  const int k = threadIdx.x;
  float acc0 = 0.f, acc1 = 0.f;
  for (int j = 0; j < D; ++j) {
    float a = A[(size_t)r * D + j];          // wave-uniform
    acc0 = fmaf(a, W2[(size_t)j * D + k], acc0);
    acc1 = fmaf(a, W2[(size_t)j * D + k + 256], acc1);
  }
  Wc[(size_t)r * D + k] = acc0;
  Wc[(size_t)r * D + k + 256] = acc1;
  float accb = 0.f;
  for (int j = k; j < D; j += 256) accb += A[(size_t)r * D + j] * b2[j];
  __shared__ float s[256];
  s[k] = accb;
  __syncthreads();
  for (int off = 128; off > 0; off >>= 1) {
    if (k < off) s[k] += s[k + off];
    __syncthreads();
  }
  if (k == 0) bc[r] = s[0] + bA[r];
}

// ---------------- GRU phase (device) ----------------
// blk2 in [0,256): row-block rb=blk2>>2 (8 rows), batch group bg=blk2&3.
// 4 waves; wave0 does x/z-part + w0h h-rows, waves 1..3 split the rest.
// THETA: wave0 runs planar flows (z-input); rb==0 publishes z and -logdet.
template<bool THETA>
__device__ __forceinline__ void gru_phase(
    int blk2, const float* __restrict__ xin, const float* __restrict__ hT,
    const float* __restrict__ Wih, const float* __restrict__ Whh,
    const float* __restrict__ bih, const float* __restrict__ bhh,
    float* __restrict__ hout, float* zT_out,
    const float* pu, const float* pw, const float* pb, float* kld_acc,
    int w0h, float (&red)[4][4][8][64]) {
  const int tid = threadIdx.x;
  const int lane = tid & 63;
  const int wv = __builtin_amdgcn_readfirstlane(tid >> 6);
  const int j0 = (blk2 >> 2) * 8;
  const int b0 = (blk2 & 3) * 64;
  const int b = b0 + lane;
  constexpr int K1 = THETA ? Z : F;

  float accR[8], accZ[8], accNX[8], accNH[8];
  #pragma unroll
  for (int r = 0; r < 8; ++r) { accR[r] = 0.f; accZ[r] = 0.f; accNX[r] = 0.f; accNH[r] = 0.f; }

  float zv[Z];
  float ld = 0.0f;

  if (wv == 0) {
    const float* wr = Wih + (size_t)(0 * H + j0) * K1;
    const float* wz = Wih + (size_t)(1 * H + j0) * K1;
    const float* wn = Wih + (size_t)(2 * H + j0) * K1;
    if (THETA) {
      #pragma unroll
      for (int i = 0; i < Z; ++i) zv[i] = xin[i * B + b];
      ld = flows_dev(zv, pu, pw, pb);
      #pragma unroll
      for (int k = 0; k < Z; k += 4) {
        #pragma unroll
        for (int r = 0; r < 8; ++r) {
          const float4 w0 = *(const float4*)(wr + r * K1 + k);
          const float4 w1 = *(const float4*)(wz + r * K1 + k);
          const float4 w2 = *(const float4*)(wn + r * K1 + k);
          accR[r]  = fmaf(w0.x, zv[k], fmaf(w0.y, zv[k+1], fmaf(w0.z, zv[k+2], fmaf(w0.w, zv[k+3], accR[r]))));
          accZ[r]  = fmaf(w1.x, zv[k], fmaf(w1.y, zv[k+1], fmaf(w1.z, zv[k+2], fmaf(w1.w, zv[k+3], accZ[r]))));
          accNX[r] = fmaf(w2.x, zv[k], fmaf(w2.y, zv[k+1], fmaf(w2.z, zv[k+2], fmaf(w2.w, zv[k+3], accNX[r]))));
        }
      }
    } else {
      for (int k = 0; k < K1; ++k) {
        float a = xin[k * B + b];
        #pragma unroll
        for (int r = 0; r < 8; ++r) {
          accR[r]  = fmaf(wr[r * K1 + k], a, accR[r]);
          accZ[r]  = fmaf(wz[r * K1 + k], a, accZ[r]);
          accNX[r] = fmaf(wn[r * K1 + k], a, accNX[r]);
        }
      }
    }
  }

  // h-part (all bounds multiples of 4)
  const int rest = (H - w0h) / 3;
  const int hlo = (wv == 0) ? 0 : w0h + (wv - 1) * rest;
  const int hhi = (wv == 0) ? w0h : hlo + rest;
  {
    const float* vr = Whh + (size_t)(0 * H + j0) * H;
    const float* vz = Whh + (size_t)(1 * H + j0) * H;
    const float* vn = Whh + (size_t)(2 * H + j0) * H;
    #pragma unroll 2
    for (int k = hlo; k < hhi; k += 4) {
      const float a0 = hT[(size_t)(k + 0) * B + b];
      const float a1 = hT[(size_t)(k + 1) * B + b];
      const float a2 = hT[(size_t)(k + 2) * B + b];
      const float a3 = hT[(size_t)(k + 3) * B + b];
      #pragma unroll
      for (int r = 0; r < 8; ++r) {
        const float4 w0 = *(const float4*)(vr + (size_t)r * H + k);
        const float4 w1 = *(const float4*)(vz + (size_t)r * H + k);
        const float4 w2 = *(const float4*)(vn + (size_t)r * H + k);
        accR[r]  = fmaf(w0.x, a0, fmaf(w0.y, a1, fmaf(w0.z, a2, fmaf(w0.w, a3, accR[r]))));
        accZ[r]  = fmaf(w1.x, a0, fmaf(w1.y, a1, fmaf(w1.z, a2, fmaf(w1.w, a3, accZ[r]))));
        accNH[r] = fmaf(w2.x, a0, fmaf(w2.y, a1, fmaf(w2.z, a2, fmaf(w2.w, a3, accNH[r]))));
      }
    }
  }

  #pragma unroll
  for (int r = 0; r < 8; ++r) {
    red[wv][0][r][lane] = accR[r];
    red[wv][1][r][lane] = accZ[r];
    red[wv][2][r][lane] = accNX[r];
    red[wv][3][r][lane] = accNH[r];
  }

  if (THETA) {
    if (wv == 0 && j0 == 0) {
      #pragma unroll
      for (int i = 0; i < Z; ++i) zT_out[i * B + b] = zv[i];
      waveReduceAtomicAdd(kld_acc, -ld, lane);
    }
  }

  __syncthreads();

  #pragma unroll
  for (int it = tid; it < 512; it += 256) {
    const int r = it >> 6, l = it & 63;
    float sR = 0.f, sZ = 0.f, sNX = 0.f, sNH = 0.f;
    #pragma unroll
    for (int w = 0; w < 4; ++w) {
      sR  += red[w][0][r][l];
      sZ  += red[w][1][r][l];
      sNX += red[w][2][r][l];
      sNH += red[w][3][r][l];
    }
    const int j = j0 + r;
    const int bb = b0 + l;
    const float rg = sigmoidf_(sR + bih[j] + bhh[j]);
    const float zg = sigmoidf_(sZ + bih[H + j] + bhh[H + j]);
    const float ng = tanhf(sNX + bih[2 * H + j] + rg * (sNH + bhh[2 * H + j]));
    const float hp = hT[(size_t)j * B + bb];
    hout[(size_t)j * B + bb] = (1.0f - zg) * ng + zg * hp;
  }
}

// ---------------- linear phase (device): 8 rows/block, K split 4 ways -------
__device__ __forceinline__ void lin8_phase(
    int blk2, const float* __restrict__ A1, int K1v,
    const float* __restrict__ A2, int K2v,
    const float* __restrict__ W, const float* __restrict__ bias,
    float* __restrict__ outp, int relu, float* shbase) {
  const int tid = threadIdx.x;
  const int lane = tid & 63;
  const int wv = __builtin_amdgcn_readfirstlane(tid >> 6);
  const int r0 = (blk2 >> 2) * 8;
  const int b0 = (blk2 & 3) * 64;
  const int b = b0 + lane;
  const int Kv = K1v + K2v;
  const int klo = wv * (Kv >> 2);
  const int khi = klo + (Kv >> 2);

  float acc[8];
  #pragma unroll
  for (int r = 0; r < 8; ++r) acc[r] = 0.f;

  const float* wbase = W + (size_t)r0 * Kv;
  {
    const int hi = khi < K1v ? khi : K1v;
    #pragma unroll 4
    for (int k = klo; k < hi; k += 4) {
      const float a0 = A1[(size_t)(k + 0) * B + b];
      const float a1 = A1[(size_t)(k + 1) * B + b];
      const float a2 = A1[(size_t)(k + 2) * B + b];
      const float a3 = A1[(size_t)(k + 3) * B + b];
      #pragma unroll
      for (int r = 0; r < 8; ++r) {
        const float4 w4 = *(const float4*)(wbase + (size_t)r * Kv + k);
        acc[r] = fmaf(w4.x, a0, fmaf(w4.y, a1, fmaf(w4.z, a2, fmaf(w4.w, a3, acc[r]))));
      }
    }
  }
  if (K2v) {
    const int lo = klo > K1v ? klo : K1v;
    for (int k = lo; k < khi; k += 4) {
      const float a0 = A2[(size_t)(k - K1v + 0) * B + b];
      const float a1 = A2[(size_t)(k - K1v + 1) * B + b];
      const float a2 = A2[(size_t)(k - K1v + 2) * B + b];
      const float a3 = A2[(size_t)(k - K1v + 3) * B + b];
      #pragma unroll
      for (int r = 0; r < 8; ++r) {
        const float4 w4 = *(const float4*)(wbase + (size_t)r * Kv + k);
        acc[r] = fmaf(w4.x, a0, fmaf(w4.y, a1, fmaf(w4.z, a2, fmaf(w4.w, a3, acc[r]))));
      }
    }
  }

  float* red = shbase;  // [4][8][64]
  #pragma unroll
  for (int r = 0; r < 8; ++r) red[(wv * 8 + r) * 64 + lane] = acc[r];
  __syncthreads();

  #pragma unroll
  for (int it = tid; it < 512; it += 256) {
    int r = it >> 6, l = it & 63;
    float s = red[(0 * 8 + r) * 64 + l] + red[(1 * 8 + r) * 64 + l]
            + red[(2 * 8 + r) * 64 + l] + red[(3 * 8 + r) * 64 + l] + bias[r0 + r];
    if (relu) s = fmaxf(s, 0.f);
    outp[(size_t)(r0 + r) * B + b0 + l] = s;
  }
}

// ---------------- z head phase (device): blk2 in [0,16) -------------------
__device__ __forceinline__ void zhead_phase(
    int blk2, const float* __restrict__ h1T,
    const float* __restrict__ Wzl, const float* __restrict__ bzl,
    const float* __restrict__ Wzs, const float* __restrict__ bzs,
    const float* __restrict__ eps_t, float* __restrict__ z0T,
    float* kld_acc, float* shbase) {
  const int tid = threadIdx.x;
  const int lane = tid & 63;
  const int wv = __builtin_amdgcn_readfirstlane(tid >> 6);
  const int z0q = (blk2 >> 2) * 4;
  const int b0 = (blk2 & 3) * 64;
  const int b = b0 + lane;
  const int klo = wv * (D >> 2), khi = klo + (D >> 2);

  const float* wp[8];
  #pragma unroll
  for (int i = 0; i < 8; ++i) {
    int zz = z0q + (i >> 1);
    wp[i] = ((i & 1) ? Wzs : Wzl) + (size_t)zz * D;
  }
  float acc[8];
  #pragma unroll
  for (int i = 0; i < 8; ++i) acc[i] = 0.f;
  #pragma unroll 4
  for (int k = klo; k < khi; k += 4) {
    const float a0 = h1T[(size_t)(k + 0) * B + b];
    const float a1 = h1T[(size_t)(k + 1) * B + b];
    const float a2 = h1T[(size_t)(k + 2) * B + b];
    const float a3 = h1T[(size_t)(k + 3) * B + b];
    #pragma unroll
    for (int i = 0; i < 8; ++i) {
      const float4 w4 = *(const float4*)(wp[i] + k);
      acc[i] = fmaf(w4.x, a0, fmaf(w4.y, a1, fmaf(w4.z, a2, fmaf(w4.w, a3, acc[i]))));
    }
  }

  float* red = shbase;  // [4][8][64]
  #pragma unroll
  for (int i = 0; i < 8; ++i) red[(wv * 8 + i) * 64 + lane] = acc[i];
  __syncthreads();

  int zi = tid >> 6, l = tid & 63;
  int zz = z0q + zi;
  int bb = b0 + l;
  float sl = red[(0 * 8 + 2 * zi) * 64 + l] + red[(1 * 8 + 2 * zi) * 64 + l]
           + red[(2 * 8 + 2 * zi) * 64 + l] + red[(3 * 8 + 2 * zi) * 64 + l] + bzl[zz];
  float ss = red[(0 * 8 + 2 * zi + 1) * 64 + l] + red[(1 * 8 + 2 * zi + 1) * 64 + l]
           + red[(2 * 8 + 2 * zi + 1) * 64 + l] + red[(3 * 8 + 2 * zi + 1) * 64 + l] + bzs[zz];
  float scale = softplusf_(ss) + 1e-6f;
  float ez = eps_t[bb * Z + zz];
  z0T[zz * B + bb] = sl + scale * ez;
  waveReduceAtomicAdd(kld_acc, -logf(scale), tid);
}

// ---------------- y head phase (device): blk2 in [0,40) -------------------
__device__ __forceinline__ void yhead_phase(
    int blk2, int t, const float* __restrict__ g1T,
    const float* __restrict__ Wyl, const float* __restrict__ byl,
    const float* __restrict__ Wys, const float* __restrict__ bys,
    const float* __restrict__ xT, float* __restrict__ out_yloc,
    float* recon_acc, float* shbase) {
  const int tid = threadIdx.x;
  const int lane = tid & 63;
  const int wv = __builtin_amdgcn_readfirstlane(tid >> 6);
  const int f0 = (blk2 >> 2) * 4;
  const int b0 = (blk2 & 3) * 64;
  const int b = b0 + lane;
  const int klo = wv * (D >> 2), khi = klo + (D >> 2);

  const float* wp[8];
  #pragma unroll
  for (int i = 0; i < 8; ++i) {
    int ff = f0 + (i >> 1);
    int fc = ff < F ? ff : 0;
    wp[i] = ((i & 1) ? Wys : Wyl) + (size_t)fc * D;
  }
  float acc[8];
  #pragma unroll
  for (int i = 0; i < 8; ++i) acc[i] = 0.f;
  #pragma unroll 4
  for (int k = klo; k < khi; k += 4) {
    const float a0 = g1T[(size_t)(k + 0) * B + b];
    const float a1 = g1T[(size_t)(k + 1) * B + b];
    const float a2 = g1T[(size_t)(k + 2) * B + b];
    const float a3 = g1T[(size_t)(k + 3) * B + b];
    #pragma unroll
    for (int i = 0; i < 8; ++i) {
      const float4 w4 = *(const float4*)(wp[i] + k);
      acc[i] = fmaf(w4.x, a0, fmaf(w4.y, a1, fmaf(w4.z, a2, fmaf(w4.w, a3, acc[i]))));
    }
  }

  float* red = shbase;  // [4][8][64]
  #pragma unroll
  for (int i = 0; i < 8; ++i) red[(wv * 8 + i) * 64 + lane] = acc[i];
  __syncthreads();

  int fi = tid >> 6, l = tid & 63;
  int ff = f0 + fi;
  int bb = b0 + l;
  float nl = 0.0f;
  if (ff < F) {
    float loc = red[(0 * 8 + 2 * fi) * 64 + l] + red[(1 * 8 + 2 * fi) * 64 + l]
              + red[(2 * 8 + 2 * fi) * 64 + l] + red[(3 * 8 + 2 * fi) * 64 + l] + byl[ff];
    float sp = red[(0 * 8 + 2 * fi + 1) * 64 + l] + red[(1 * 8 + 2 * fi + 1) * 64 + l]
             + red[(2 * 8 + 2 * fi + 1) * 64 + l] + red[(3 * 8 + 2 * fi + 1) * 64 + l] + bys[ff];
    float scale = softplusf_(sp) + 1e-6f;
    out_yloc[((size_t)bb * L + t) * F + ff] = loc;
    float xv = xT[((size_t)t * F + ff) * B + bb];
    float d = (xv - loc) / scale;
    nl = 0.5f * d * d + logf(scale) + 0.5f * LOG2PI_F;
  }
  waveReduceAtomicAdd(recon_acc, nl, tid);
}

// ---------------- persistent kernel: whole recurrence, 3 phases/step -------
struct PP {
  const float *xT, *eps_z;
  const float *phi_Wih, *phi_Whh, *phi_bih, *phi_bhh, *phi_W1, *phi_b1;
  const float *th_Wih, *th_Whh, *th_bih, *th_bhh, *th_W1, *th_b1;
  const float *Wzl, *bzl, *Wzs, *bzs, *Wyl, *byl, *Wys, *bys;
  const float *pu, *pw, *pb;
  float *hphi0, *hphi1, *hth0, *hth1, *zT, *z0T, *h1T, *g1T, *acc, *out;
  uint32_t* bar;
};

__global__ __launch_bounds__(256, 2) void k_persist(PP P) {
  __shared__ float red[4][4][8][64];  // 32 KB; reused (flat) by lin/head phases
  const int blk = blockIdx.x;
  float* sh = &red[0][0][0][0];

  for (int t = 0; t <= L; ++t) {
    float* hphi_c = (t & 1) ? P.hphi1 : P.hphi0;
    float* hphi_n = (t & 1) ? P.hphi0 : P.hphi1;
    float* hth_c  = (t & 1) ? P.hth1 : P.hth0;   // th_h(t-2)
    float* hth_n  = (t & 1) ? P.hth0 : P.hth1;   // th_h(t-1)

    // ---- phase A: phiGRU(t) || thetaGRU(t-1)+flows ----
    if (blk < 256) {
      if (t < L)
        gru_phase<false>(blk, P.xT + (size_t)t * F * B, hphi_c,
                         P.phi_Wih, P.phi_Whh, P.phi_bih, P.phi_bhh,
                         hphi_n, nullptr, nullptr, nullptr, nullptr, nullptr,
                         92, red);
    } else {
      if (t >= 1)
        gru_phase<true>(blk - 256, P.z0T, hth_c,
                        P.th_Wih, P.th_Whh, P.th_bih, P.th_bhh,
                        hth_n, P.zT, P.pu, P.pw, P.pb, P.acc,
                        80, red);
    }
    grid_sync_(P.bar);

    // ---- phase B: MLP1(t) || thetaMLP1(t-1) ----
    if (blk < 256) {
      if (t < L)
        lin8_phase(blk, hphi_n, H, P.zT, Z, P.phi_W1, P.phi_b1, P.h1T, 1, sh);
    } else {
      if (t >= 1)
        lin8_phase(blk - 256, hth_n, H, nullptr, 0, P.th_W1, P.th_b1, P.g1T, 1, sh);
    }
    grid_sync_(P.bar);

    // ---- phase C: zhead(t) || yhead(t-1) ----
    if (blk < 16) {
      if (t < L)
        zhead_phase(blk, P.h1T, P.Wzl, P.bzl, P.Wzs, P.bzs,
                    P.eps_z + (size_t)t * B * Z, P.z0T, P.acc, sh);
    } else if (blk >= 64 && blk < 104) {
      if (t >= 1)
        yhead_phase(blk - 64, t - 1, P.g1T, P.Wyl, P.byl, P.Wys, P.bys,
                    P.xT, P.out, P.acc + 1, sh);
    }
    if (t < L) grid_sync_(P.bar);
  }
}

}  // namespace

extern "C" void kernel_launch(void* const* d_in, const int* in_sizes, int n_in,
                              void* d_out, int out_size, void* d_ws, size_t ws_size,
                              hipStream_t stream) {
  const float* x        = (const float*)d_in[0];
  const float* phi_Wih  = (const float*)d_in[1];
  const float* phi_Whh  = (const float*)d_in[2];
  const float* phi_bih  = (const float*)d_in[3];
  const float* phi_bhh  = (const float*)d_in[4];
  const float* phi_W1   = (const float*)d_in[5];
  const float* phi_b1   = (const float*)d_in[6];
  const float* phi_W2   = (const float*)d_in[7];
  const float* phi_b2   = (const float*)d_in[8];
  const float* zloc_W   = (const float*)d_in[9];
  const float* zloc_b   = (const float*)d_in[10];
  const float* zscale_W = (const float*)d_in[11];
  const float* zscale_b = (const float*)d_in[12];
  const float* pu       = (const float*)d_in[13];
  const float* pw       = (const float*)d_in[14];
  const float* pb       = (const float*)d_in[15];
  const float* th_Wih   = (const float*)d_in[16];
  const float* th_Whh   = (const float*)d_in[17];
  const float* th_bih   = (const float*)d_in[18];
  const float* th_bhh   = (const float*)d_in[19];
  const float* th_W1    = (const float*)d_in[20];
  const float* th_b1    = (const float*)d_in[21];
  const float* th_W2    = (const float*)d_in[22];
  const float* th_b2    = (const float*)d_in[23];
  const float* xloc_W   = (const float*)d_in[24];
  const float* xloc_b   = (const float*)d_in[25];
  const float* xscale_W = (const float*)d_in[26];
  const float* xscale_b = (const float*)d_in[27];

  float* out = (float*)d_out;
  float* ws = (float*)d_ws;

  // workspace layout (floats; generous alignment)
  float* acc   = ws;                        // [0]=kld, [1]=recon
  uint32_t* bar = (uint32_t*)(ws + 32);     // barrier state (separate cacheline)
  float* eps_z = ws + 64;                   // LBZ
  float* xT    = eps_z + LBZ;               // LFB
  float* hphi0 = xT + LFB;                  // HB
  float* hphi1 = hphi0 + HB;                // HB
  float* hth0  = hphi1 + HB;                // HB
  float* hth1  = hth0 + HB;                 // HB
  float* zT    = hth1 + HB;                 // ZB
  float* z0T   = zT + ZB;                   // ZB
  float* h1T   = z0T + ZB;                  // DB
  float* g1T   = h1T + DB;                  // DB
  float* Wzl   = g1T + DB;                  // Z*D
  float* Wzs   = Wzl + Z * D;               // Z*D
  float* bzl   = Wzs + Z * D;               // 64
  float* bzs   = bzl + 64;                  // 64
  float* Wyl   = bzs + 64;                  // F*D
  float* Wys   = Wyl + F * D;               // F*D
  float* byl   = Wys + F * D;               // 64
  float* bys   = byl + 64;                  // 64

  hipMemsetAsync(acc, 0, 64 * sizeof(float), stream);   // zeroes acc + bar
  hipMemsetAsync(hphi0, 0, (size_t)HB * sizeof(float), stream);
  hipMemsetAsync(hth1, 0, (size_t)HB * sizeof(float), stream);   // th_h(-1)
  hipMemsetAsync(zT, 0, (size_t)ZB * sizeof(float), stream);     // z(-1)

  // JAX PRNG: key(42)=(0,42); split -> kz, kp
  uint32_t a0, a1, b0, b1;
  threefry2x32_(0u, 42u, 0u, 2u, a0, a1);
  threefry2x32_(0u, 42u, 1u, 3u, b0, b1);
  const uint32_t kz0 = a0, kz1 = b0, kp0 = a1, kp1 = b1;

  k_transpose_x<<<(B * L * F) / 256, 256, 0, stream>>>(x, xT);
  k_noise<<<HALF / 256, 256, 0, stream>>>(eps_z, acc, kz0, kz1, kp0, kp1);

  // Compose linear MLP2 into the z/y heads: Wc = headW @ W2, bc = headW @ b2 + headb.
  k_compose<<<Z, 256, 0, stream>>>(zloc_W, zloc_b, phi_W2, phi_b2, Wzl, bzl);
  k_compose<<<Z, 256, 0, stream>>>(zscale_W, zscale_b, phi_W2, phi_b2, Wzs, bzs);
  k_compose<<<F, 256, 0, stream>>>(xloc_W, xloc_b, th_W2, th_b2, Wyl, byl);
  k_compose<<<F, 256, 0, stream>>>(xscale_W, xscale_b, th_W2, th_b2, Wys, bys);

  PP P;
  P.xT = xT; P.eps_z = eps_z;
  P.phi_Wih = phi_Wih; P.phi_Whh = phi_Whh; P.phi_bih = phi_bih; P.phi_bhh = phi_bhh;
  P.phi_W1 = phi_W1; P.phi_b1 = phi_b1;
  P.th_Wih = th_Wih; P.th_Whh = th_Whh; P.th_bih = th_bih; P.th_bhh = th_bhh;
  P.th_W1 = th_W1; P.th_b1 = th_b1;
  P.Wzl = Wzl; P.bzl = bzl; P.Wzs = Wzs; P.bzs = bzs;
  P.Wyl = Wyl; P.byl = byl; P.Wys = Wys; P.bys = bys;
  P.pu = pu; P.pw = pw; P.pb = pb;
  P.hphi0 = hphi0; P.hphi1 = hphi1; P.hth0 = hth0; P.hth1 = hth1;
  P.zT = zT; P.z0T = z0T; P.h1T = h1T; P.g1T = g1T;
  P.acc = acc; P.out = out; P.bar = bar;

  k_persist<<<GRIDN, 256, 0, stream>>>(P);

  k_finalize<<<1, 1, 0, stream>>>(acc, out);
}

// Round 3
// 27376.642 us; speedup vs baseline: 2.6847x; 2.6847x over previous
//
#include <hip/hip_runtime.h>
#include <stdint.h>
#include <math.h>

namespace {

constexpr int B = 256, L = 256, F = 38, H = 512, D = 512, Z = 16, NF = 20;
constexpr float LOG2PI_F = 1.8378770664093453f;
constexpr int LBZ = L * B * Z;      // 1048576
constexpr int HALF = LBZ / 2;       // 524288
constexpr int HB = H * B;           // 131072
constexpr int DB = D * B;           // 131072
constexpr int ZB = Z * B;           // 4096
constexpr int LFB = L * F * B;      // 2490368

// ---------------- math helpers ----------------

__device__ __forceinline__ float sigmoidf_(float x) {
  return 1.0f / (1.0f + expf(-x));
}
__device__ __forceinline__ float softplusf_(float x) {
  return fmaxf(x, 0.0f) + log1pf(expf(-fabsf(x)));
}

__device__ __forceinline__ void waveReduceAtomicAdd(float* dst, float v, int tid) {
  #pragma unroll
  for (int off = 32; off > 0; off >>= 1) v += __shfl_down(v, off, 64);
  if ((tid & 63) == 0) atomicAdd(dst, v);
}

// ---------------- threefry2x32 (JAX-compatible) ----------------

__host__ __device__ inline uint32_t rotl32_(uint32_t x, int d) {
  return (x << d) | (x >> (32 - d));
}

__host__ __device__ inline void threefry2x32_(uint32_t k0, uint32_t k1,
                                              uint32_t x0, uint32_t x1,
                                              uint32_t& o0, uint32_t& o1) {
  const uint32_t ks2 = k0 ^ k1 ^ 0x1BD11BDAu;
  uint32_t v0 = x0 + k0;
  uint32_t v1 = x1 + k1;
#define TF_RND(r) { v0 += v1; v1 = rotl32_(v1, r); v1 ^= v0; }
  TF_RND(13) TF_RND(15) TF_RND(26) TF_RND(6)
  v0 += k1;  v1 += ks2 + 1u;
  TF_RND(17) TF_RND(29) TF_RND(16) TF_RND(24)
  v0 += ks2; v1 += k0 + 2u;
  TF_RND(13) TF_RND(15) TF_RND(26) TF_RND(6)
  v0 += k0;  v1 += k1 + 3u;
  TF_RND(17) TF_RND(29) TF_RND(16) TF_RND(24)
  v0 += k1;  v1 += ks2 + 4u;
  TF_RND(13) TF_RND(15) TF_RND(26) TF_RND(6)
  v0 += ks2; v1 += k0 + 5u;
#undef TF_RND
  o0 = v0; o1 = v1;
}

__device__ __forceinline__ float erfinv_f_(float x) {
  float w = -log1pf(-x * x);
  float p;
  if (w < 5.0f) {
    w -= 2.5f;
    p = 2.81022636e-08f;
    p = fmaf(p, w, 3.43273939e-07f);
    p = fmaf(p, w, -3.5233877e-06f);
    p = fmaf(p, w, -4.39150654e-06f);
    p = fmaf(p, w, 0.00021858087f);
    p = fmaf(p, w, -0.00125372503f);
    p = fmaf(p, w, -0.00417768164f);
    p = fmaf(p, w, 0.246640727f);
    p = fmaf(p, w, 1.50140941f);
  } else {
    w = sqrtf(w) - 3.0f;
    p = -0.000200214257f;
    p = fmaf(p, w, 0.000100950558f);
    p = fmaf(p, w, 0.00134934322f);
    p = fmaf(p, w, -0.00367342844f);
    p = fmaf(p, w, 0.00573950773f);
    p = fmaf(p, w, -0.0076224613f);
    p = fmaf(p, w, 0.00943887047f);
    p = fmaf(p, w, 1.00167406f);
    p = fmaf(p, w, 2.83297682f);
  }
  return p * x;
}

__device__ __forceinline__ float bits_to_normal_(uint32_t bits) {
  uint32_t m = (bits >> 9) | 0x3f800000u;
  float f = __uint_as_float(m) - 1.0f;
  float u = f * 2.0f + (-0.99999994f);
  u = fmaxf(-0.99999994f, u);
  return 1.41421356f * erfinv_f_(u);
}

// planar flows for one batch column (per-lane), returns logdet; zv updated in place
__device__ __forceinline__ float flows_dev(float zv[Z], const float* __restrict__ pu,
                                           const float* __restrict__ pw,
                                           const float* __restrict__ pb) {
  float ld = 0.0f;
  for (int f = 0; f < NF; ++f) {
    const float* w = pw + f * Z;
    const float* u = pu + f * Z;
    float wn2 = 0.0f, wu = 0.0f;
    #pragma unroll
    for (int i = 0; i < Z; ++i) { wn2 = fmaf(w[i], w[i], wn2); wu = fmaf(w[i], u[i], wu); }
    float coef = (softplusf_(wu) - 1.0f - wu) / wn2;
    float a_in = pb[f];
    #pragma unroll
    for (int i = 0; i < Z; ++i) a_in = fmaf(zv[i], w[i], a_in);
    float a = tanhf(a_in);
    float uw = 0.0f;
    #pragma unroll
    for (int i = 0; i < Z; ++i) {
      float uh = fmaf(coef, w[i], u[i]);
      uw = fmaf(uh, w[i], uw);
      zv[i] = fmaf(uh, a, zv[i]);
    }
    ld += logf(fabsf(1.0f + (1.0f - a * a) * uw) + 1e-12f);
  }
  return ld;
}

// ---------------- small utility kernels ----------------

__global__ __launch_bounds__(256) void k_transpose_x(const float* __restrict__ x,
                                                     float* __restrict__ xT) {
  int idx = blockIdx.x * blockDim.x + threadIdx.x;  // over B*L*F
  int f = idx % F;
  int t = (idx / F) % L;
  int b = idx / (F * L);
  xT[(t * F + f) * B + b] = x[idx];
}

__global__ __launch_bounds__(256) void k_noise(float* __restrict__ eps_z,
                                               float* __restrict__ kld_acc,
                                               uint32_t kz0, uint32_t kz1,
                                               uint32_t kp0, uint32_t kp1) {
  int i = blockIdx.x * blockDim.x + threadIdx.x;  // [0, HALF)
  uint32_t a0, a1, b0, b1;
  threefry2x32_(kz0, kz1, (uint32_t)i, (uint32_t)(i + HALF), a0, a1);
  float ez0 = bits_to_normal_(a0);
  float ez1 = bits_to_normal_(a1);
  eps_z[i] = ez0;
  eps_z[i + HALF] = ez1;
  threefry2x32_(kp0, kp1, (uint32_t)i, (uint32_t)(i + HALF), b0, b1);
  float ep0 = bits_to_normal_(b0);
  float ep1 = bits_to_normal_(b1);
  float local = -0.5f * (ez0 * ez0 + ez1 * ez1) + 0.5f * (ep0 * ep0 + ep1 * ep1);
  waveReduceAtomicAdd(kld_acc, local, threadIdx.x);
}

__global__ void k_finalize(const float* __restrict__ acc, float* __restrict__ out) {
  out[(size_t)B * L * F] = acc[1];      // recon
  out[(size_t)B * L * F + 1] = acc[0];  // kld
}

// ---------------- weight composition (once per launch) ----------------
// Wc[r][k] = sum_j A[r][j] * W2[j][k]; bc[r] = sum_j A[r][j]*b2[j] + bA[r]
__global__ __launch_bounds__(256) void k_compose(
    const float* __restrict__ A, const float* __restrict__ bA,
    const float* __restrict__ W2, const float* __restrict__ b2,
    float* __restrict__ Wc, float* __restrict__ bc) {
  const int r = blockIdx.x;
  const int k = threadIdx.x;
  float acc0 = 0.f, acc1 = 0.f;
  for (int j = 0; j < D; ++j) {
    float a = A[(size_t)r * D + j];          // wave-uniform
    acc0 = fmaf(a, W2[(size_t)j * D + k], acc0);
    acc1 = fmaf(a, W2[(size_t)j * D + k + 256], acc1);
  }
  Wc[(size_t)r * D + k] = acc0;
  Wc[(size_t)r * D + k + 256] = acc1;
  float accb = 0.f;
  for (int j = k; j < D; j += 256) accb += A[(size_t)r * D + j] * b2[j];
  __shared__ float s[256];
  s[k] = accb;
  __syncthreads();
  for (int off = 128; off > 0; off >>= 1) {
    if (k < off) s[k] += s[k + off];
    __syncthreads();
  }
  if (k == 0) bc[r] = s[0] + bA[r];
}

// ---------------- GRU phase (device) ----------------
// blk2 in [0,256): row-block rb=blk2>>2 (8 rows), batch group bg=blk2&3.
// 4 waves; wave0 does x/z-part + w0h h-rows, waves 1..3 split the rest.
// THETA: wave0 runs planar flows (z-input); j0==0 publishes -logdet kld.
template<bool THETA>
__device__ __forceinline__ void gru_phase(
    int blk2, const float* __restrict__ xin, const float* __restrict__ hT,
    const float* __restrict__ Wih, const float* __restrict__ Whh,
    const float* __restrict__ bih, const float* __restrict__ bhh,
    float* __restrict__ hout,
    const float* pu, const float* pw, const float* pb, float* kld_acc,
    int w0h, float (&red)[4][4][8][64]) {
  const int tid = threadIdx.x;
  const int lane = tid & 63;
  const int wv = __builtin_amdgcn_readfirstlane(tid >> 6);
  const int j0 = (blk2 >> 2) * 8;
  const int b0 = (blk2 & 3) * 64;
  const int b = b0 + lane;
  constexpr int K1 = THETA ? Z : F;

  float accR[8], accZ[8], accNX[8], accNH[8];
  #pragma unroll
  for (int r = 0; r < 8; ++r) { accR[r] = 0.f; accZ[r] = 0.f; accNX[r] = 0.f; accNH[r] = 0.f; }

  float zv[Z];
  float ld = 0.0f;

  if (wv == 0) {
    const float* wr = Wih + (size_t)(0 * H + j0) * K1;
    const float* wz = Wih + (size_t)(1 * H + j0) * K1;
    const float* wn = Wih + (size_t)(2 * H + j0) * K1;
    if (THETA) {
      #pragma unroll
      for (int i = 0; i < Z; ++i) zv[i] = xin[i * B + b];
      ld = flows_dev(zv, pu, pw, pb);
      #pragma unroll
      for (int k = 0; k < Z; k += 4) {
        #pragma unroll
        for (int r = 0; r < 8; ++r) {
          const float4 w0 = *(const float4*)(wr + r * K1 + k);
          const float4 w1 = *(const float4*)(wz + r * K1 + k);
          const float4 w2 = *(const float4*)(wn + r * K1 + k);
          accR[r]  = fmaf(w0.x, zv[k], fmaf(w0.y, zv[k+1], fmaf(w0.z, zv[k+2], fmaf(w0.w, zv[k+3], accR[r]))));
          accZ[r]  = fmaf(w1.x, zv[k], fmaf(w1.y, zv[k+1], fmaf(w1.z, zv[k+2], fmaf(w1.w, zv[k+3], accZ[r]))));
          accNX[r] = fmaf(w2.x, zv[k], fmaf(w2.y, zv[k+1], fmaf(w2.z, zv[k+2], fmaf(w2.w, zv[k+3], accNX[r]))));
        }
      }
    } else {
      for (int k = 0; k < K1; ++k) {
        float a = xin[k * B + b];
        #pragma unroll
        for (int r = 0; r < 8; ++r) {
          accR[r]  = fmaf(wr[r * K1 + k], a, accR[r]);
          accZ[r]  = fmaf(wz[r * K1 + k], a, accZ[r]);
          accNX[r] = fmaf(wn[r * K1 + k], a, accNX[r]);
        }
      }
    }
  }

  // h-part (all bounds multiples of 4)
  const int rest = (H - w0h) / 3;
  const int hlo = (wv == 0) ? 0 : w0h + (wv - 1) * rest;
  const int hhi = (wv == 0) ? w0h : hlo + rest;
  {
    const float* vr = Whh + (size_t)(0 * H + j0) * H;
    const float* vz = Whh + (size_t)(1 * H + j0) * H;
    const float* vn = Whh + (size_t)(2 * H + j0) * H;
    #pragma unroll 2
    for (int k = hlo; k < hhi; k += 4) {
      const float a0 = hT[(size_t)(k + 0) * B + b];
      const float a1 = hT[(size_t)(k + 1) * B + b];
      const float a2 = hT[(size_t)(k + 2) * B + b];
      const float a3 = hT[(size_t)(k + 3) * B + b];
      #pragma unroll
      for (int r = 0; r < 8; ++r) {
        const float4 w0 = *(const float4*)(vr + (size_t)r * H + k);
        const float4 w1 = *(const float4*)(vz + (size_t)r * H + k);
        const float4 w2 = *(const float4*)(vn + (size_t)r * H + k);
        accR[r]  = fmaf(w0.x, a0, fmaf(w0.y, a1, fmaf(w0.z, a2, fmaf(w0.w, a3, accR[r]))));
        accZ[r]  = fmaf(w1.x, a0, fmaf(w1.y, a1, fmaf(w1.z, a2, fmaf(w1.w, a3, accZ[r]))));
        accNH[r] = fmaf(w2.x, a0, fmaf(w2.y, a1, fmaf(w2.z, a2, fmaf(w2.w, a3, accNH[r]))));
      }
    }
  }

  #pragma unroll
  for (int r = 0; r < 8; ++r) {
    red[wv][0][r][lane] = accR[r];
    red[wv][1][r][lane] = accZ[r];
    red[wv][2][r][lane] = accNX[r];
    red[wv][3][r][lane] = accNH[r];
  }

  if (THETA) {
    if (wv == 0 && j0 == 0) {
      waveReduceAtomicAdd(kld_acc, -ld, lane);
    }
  }

  __syncthreads();

  #pragma unroll
  for (int it = tid; it < 512; it += 256) {
    const int r = it >> 6, l = it & 63;
    float sR = 0.f, sZ = 0.f, sNX = 0.f, sNH = 0.f;
    #pragma unroll
    for (int w = 0; w < 4; ++w) {
      sR  += red[w][0][r][l];
      sZ  += red[w][1][r][l];
      sNX += red[w][2][r][l];
      sNH += red[w][3][r][l];
    }
    const int j = j0 + r;
    const int bb = b0 + l;
    const float rg = sigmoidf_(sR + bih[j] + bhh[j]);
    const float zg = sigmoidf_(sZ + bih[H + j] + bhh[H + j]);
    const float ng = tanhf(sNX + bih[2 * H + j] + rg * (sNH + bhh[2 * H + j]));
    const float hp = hT[(size_t)j * B + bb];
    hout[(size_t)j * B + bb] = (1.0f - zg) * ng + zg * hp;
  }
}

// ---------------- linear phase (device): 8 rows/block, K split 4 ways -------
__device__ __forceinline__ void lin8_phase(
    int blk2, const float* __restrict__ A1, int K1v,
    const float* __restrict__ W, const float* __restrict__ bias,
    float* __restrict__ outp, int relu, float* shbase) {
  const int tid = threadIdx.x;
  const int lane = tid & 63;
  const int wv = __builtin_amdgcn_readfirstlane(tid >> 6);
  const int r0 = (blk2 >> 2) * 8;
  const int b0 = (blk2 & 3) * 64;
  const int b = b0 + lane;
  const int Kv = K1v;
  const int klo = wv * (Kv >> 2);
  const int khi = klo + (Kv >> 2);

  float acc[8];
  #pragma unroll
  for (int r = 0; r < 8; ++r) acc[r] = 0.f;

  const float* wbase = W + (size_t)r0 * Kv;
  #pragma unroll 4
  for (int k = klo; k < khi; k += 4) {
    const float a0 = A1[(size_t)(k + 0) * B + b];
    const float a1 = A1[(size_t)(k + 1) * B + b];
    const float a2 = A1[(size_t)(k + 2) * B + b];
    const float a3 = A1[(size_t)(k + 3) * B + b];
    #pragma unroll
    for (int r = 0; r < 8; ++r) {
      const float4 w4 = *(const float4*)(wbase + (size_t)r * Kv + k);
      acc[r] = fmaf(w4.x, a0, fmaf(w4.y, a1, fmaf(w4.z, a2, fmaf(w4.w, a3, acc[r]))));
    }
  }

  float* red = shbase;  // [4][8][64]
  #pragma unroll
  for (int r = 0; r < 8; ++r) red[(wv * 8 + r) * 64 + lane] = acc[r];
  __syncthreads();

  #pragma unroll
  for (int it = tid; it < 512; it += 256) {
    int r = it >> 6, l = it & 63;
    float s = red[(0 * 8 + r) * 64 + l] + red[(1 * 8 + r) * 64 + l]
            + red[(2 * 8 + r) * 64 + l] + red[(3 * 8 + r) * 64 + l] + bias[r0 + r];
    if (relu) s = fmaxf(s, 0.f);
    outp[(size_t)(r0 + r) * B + b0 + l] = s;
  }
}

// ---------------- phi MLP1 phase with in-register flows -------------------
// h1 = relu(W1 @ concat(phi_h, flows(z0_prev)) + b1). Waves 0-2: 140 h-rows
// each; wave3: 92 h-rows + recompute flows(z0_prev) in regs + 16 z-rows.
// flows arithmetic identical to theta GRU's (bitwise same z values).
__device__ __forceinline__ void mlp1_phi_phase(
    int blk2, const float* __restrict__ hphiT, const float* __restrict__ z0prev,
    const float* __restrict__ W, const float* __restrict__ bias,
    float* __restrict__ h1T,
    const float* pu, const float* pw, const float* pb, float* shbase) {
  const int tid = threadIdx.x;
  const int lane = tid & 63;
  const int wv = __builtin_amdgcn_readfirstlane(tid >> 6);
  const int r0 = (blk2 >> 2) * 8;
  const int b0 = (blk2 & 3) * 64;
  const int b = b0 + lane;
  constexpr int Kv = H + Z;  // 528
  const int klo = wv * 140;
  const int khi = (wv == 3) ? H : klo + 140;

  float acc[8];
  #pragma unroll
  for (int r = 0; r < 8; ++r) acc[r] = 0.f;

  const float* wbase = W + (size_t)r0 * Kv;
  #pragma unroll 4
  for (int k = klo; k < khi; k += 4) {
    const float a0 = hphiT[(size_t)(k + 0) * B + b];
    const float a1 = hphiT[(size_t)(k + 1) * B + b];
    const float a2 = hphiT[(size_t)(k + 2) * B + b];
    const float a3 = hphiT[(size_t)(k + 3) * B + b];
    #pragma unroll
    for (int r = 0; r < 8; ++r) {
      const float4 w4 = *(const float4*)(wbase + (size_t)r * Kv + k);
      acc[r] = fmaf(w4.x, a0, fmaf(w4.y, a1, fmaf(w4.z, a2, fmaf(w4.w, a3, acc[r]))));
    }
  }
  if (wv == 3 && z0prev != nullptr) {   // t==0: z_prev == 0 -> zero contribution
    float zv[Z];
    #pragma unroll
    for (int i = 0; i < Z; ++i) zv[i] = z0prev[i * B + b];
    flows_dev(zv, pu, pw, pb);
    #pragma unroll
    for (int i = 0; i < Z; i += 4) {
      #pragma unroll
      for (int r = 0; r < 8; ++r) {
        const float4 w4 = *(const float4*)(wbase + (size_t)r * Kv + H + i);
        acc[r] = fmaf(w4.x, zv[i], fmaf(w4.y, zv[i+1], fmaf(w4.z, zv[i+2], fmaf(w4.w, zv[i+3], acc[r]))));
      }
    }
  }

  float* red = shbase;  // [4][8][64]
  #pragma unroll
  for (int r = 0; r < 8; ++r) red[(wv * 8 + r) * 64 + lane] = acc[r];
  __syncthreads();

  #pragma unroll
  for (int it = tid; it < 512; it += 256) {
    int r = it >> 6, l = it & 63;
    float s = red[(0 * 8 + r) * 64 + l] + red[(1 * 8 + r) * 64 + l]
            + red[(2 * 8 + r) * 64 + l] + red[(3 * 8 + r) * 64 + l] + bias[r0 + r];
    s = fmaxf(s, 0.f);
    h1T[(size_t)(r0 + r) * B + b0 + l] = s;
  }
}

// ---------------- z head phase (device): blk2 in [0,16) -------------------
__device__ __forceinline__ void zhead_phase(
    int blk2, const float* __restrict__ h1T,
    const float* __restrict__ Wzl, const float* __restrict__ bzl,
    const float* __restrict__ Wzs, const float* __restrict__ bzs,
    const float* __restrict__ eps_t, float* __restrict__ z0T,
    float* kld_acc, float* shbase) {
  const int tid = threadIdx.x;
  const int lane = tid & 63;
  const int wv = __builtin_amdgcn_readfirstlane(tid >> 6);
  const int z0q = (blk2 >> 2) * 4;
  const int b0 = (blk2 & 3) * 64;
  const int b = b0 + lane;
  const int klo = wv * (D >> 2), khi = klo + (D >> 2);

  const float* wp[8];
  #pragma unroll
  for (int i = 0; i < 8; ++i) {
    int zz = z0q + (i >> 1);
    wp[i] = ((i & 1) ? Wzs : Wzl) + (size_t)zz * D;
  }
  float acc[8];
  #pragma unroll
  for (int i = 0; i < 8; ++i) acc[i] = 0.f;
  #pragma unroll 4
  for (int k = klo; k < khi; k += 4) {
    const float a0 = h1T[(size_t)(k + 0) * B + b];
    const float a1 = h1T[(size_t)(k + 1) * B + b];
    const float a2 = h1T[(size_t)(k + 2) * B + b];
    const float a3 = h1T[(size_t)(k + 3) * B + b];
    #pragma unroll
    for (int i = 0; i < 8; ++i) {
      const float4 w4 = *(const float4*)(wp[i] + k);
      acc[i] = fmaf(w4.x, a0, fmaf(w4.y, a1, fmaf(w4.z, a2, fmaf(w4.w, a3, acc[i]))));
    }
  }

  float* red = shbase;  // [4][8][64]
  #pragma unroll
  for (int i = 0; i < 8; ++i) red[(wv * 8 + i) * 64 + lane] = acc[i];
  __syncthreads();

  int zi = tid >> 6, l = tid & 63;
  int zz = z0q + zi;
  int bb = b0 + l;
  float sl = red[(0 * 8 + 2 * zi) * 64 + l] + red[(1 * 8 + 2 * zi) * 64 + l]
           + red[(2 * 8 + 2 * zi) * 64 + l] + red[(3 * 8 + 2 * zi) * 64 + l] + bzl[zz];
  float ss = red[(0 * 8 + 2 * zi + 1) * 64 + l] + red[(1 * 8 + 2 * zi + 1) * 64 + l]
           + red[(2 * 8 + 2 * zi + 1) * 64 + l] + red[(3 * 8 + 2 * zi + 1) * 64 + l] + bzs[zz];
  float scale = softplusf_(ss) + 1e-6f;
  float ez = eps_t[bb * Z + zz];
  z0T[zz * B + bb] = sl + scale * ez;
  waveReduceAtomicAdd(kld_acc, -logf(scale), tid);
}

// ---------------- y head phase (device): blk2 in [0,40) -------------------
__device__ __forceinline__ void yhead_phase(
    int blk2, int t, const float* __restrict__ g1T,
    const float* __restrict__ Wyl, const float* __restrict__ byl,
    const float* __restrict__ Wys, const float* __restrict__ bys,
    const float* __restrict__ xT, float* __restrict__ out_yloc,
    float* recon_acc, float* shbase) {
  const int tid = threadIdx.x;
  const int lane = tid & 63;
  const int wv = __builtin_amdgcn_readfirstlane(tid >> 6);
  const int f0 = (blk2 >> 2) * 4;
  const int b0 = (blk2 & 3) * 64;
  const int b = b0 + lane;
  const int klo = wv * (D >> 2), khi = klo + (D >> 2);

  const float* wp[8];
  #pragma unroll
  for (int i = 0; i < 8; ++i) {
    int ff = f0 + (i >> 1);
    int fc = ff < F ? ff : 0;
    wp[i] = ((i & 1) ? Wys : Wyl) + (size_t)fc * D;
  }
  float acc[8];
  #pragma unroll
  for (int i = 0; i < 8; ++i) acc[i] = 0.f;
  #pragma unroll 4
  for (int k = klo; k < khi; k += 4) {
    const float a0 = g1T[(size_t)(k + 0) * B + b];
    const float a1 = g1T[(size_t)(k + 1) * B + b];
    const float a2 = g1T[(size_t)(k + 2) * B + b];
    const float a3 = g1T[(size_t)(k + 3) * B + b];
    #pragma unroll
    for (int i = 0; i < 8; ++i) {
      const float4 w4 = *(const float4*)(wp[i] + k);
      acc[i] = fmaf(w4.x, a0, fmaf(w4.y, a1, fmaf(w4.z, a2, fmaf(w4.w, a3, acc[i]))));
    }
  }

  float* red = shbase;  // [4][8][64]
  #pragma unroll
  for (int i = 0; i < 8; ++i) red[(wv * 8 + i) * 64 + lane] = acc[i];
  __syncthreads();

  int fi = tid >> 6, l = tid & 63;
  int ff = f0 + fi;
  int bb = b0 + l;
  float nl = 0.0f;
  if (ff < F) {
    float loc = red[(0 * 8 + 2 * fi) * 64 + l] + red[(1 * 8 + 2 * fi) * 64 + l]
              + red[(2 * 8 + 2 * fi) * 64 + l] + red[(3 * 8 + 2 * fi) * 64 + l] + byl[ff];
    float sp = red[(0 * 8 + 2 * fi + 1) * 64 + l] + red[(1 * 8 + 2 * fi + 1) * 64 + l]
             + red[(2 * 8 + 2 * fi + 1) * 64 + l] + red[(3 * 8 + 2 * fi + 1) * 64 + l] + bys[ff];
    float scale = softplusf_(sp) + 1e-6f;
    out_yloc[((size_t)bb * L + t) * F + ff] = loc;
    float xv = xT[((size_t)t * F + ff) * B + bb];
    float d = (xv - loc) / scale;
    nl = 0.5f * d * d + logf(scale) + 0.5f * LOG2PI_F;
  }
  waveReduceAtomicAdd(recon_acc, nl, tid);
}

// ---------------- constant pointer bundle ----------------
struct CW {
  const float *phi_Wih, *phi_Whh, *phi_bih, *phi_bhh, *phi_W1, *phi_b1;
  const float *th_Wih, *th_Whh, *th_bih, *th_bhh, *th_W1, *th_b1;
  const float *Wzl, *bzl, *Wzs, *bzs, *Wyl, *byl, *Wys, *bys;
  const float *pu, *pw, *pb, *xT;
  float *acc, *out, *h1T, *g1T;
};

// ---------------- launch A: phiGRU(i) | thGRU(i-2) | zhead(i-1) | yhead(i-3)
__global__ __launch_bounds__(256) void kA(
    CW C, const float* xt, const float* phi_c, float* phi_n,
    const float* z0_in, const float* th_c, float* th_n,
    float* z0_out, const float* eps_t, int t_y,
    int hasPhi, int hasTh, int hasZ, int hasY) {
  __shared__ float red[4][4][8][64];  // 32 KB (flat reuse by small phases)
  float* sh = &red[0][0][0][0];
  const int blk = blockIdx.x;
  if (blk < 256) {
    if (hasPhi)
      gru_phase<false>(blk, xt, phi_c, C.phi_Wih, C.phi_Whh, C.phi_bih, C.phi_bhh,
                       phi_n, nullptr, nullptr, nullptr, nullptr, 104, red);
  } else if (blk < 512) {
    if (hasTh)
      gru_phase<true>(blk - 256, z0_in, th_c, C.th_Wih, C.th_Whh, C.th_bih, C.th_bhh,
                      th_n, C.pu, C.pw, C.pb, C.acc, 56, red);
  } else if (blk < 528) {
    if (hasZ)
      zhead_phase(blk - 512, C.h1T, C.Wzl, C.bzl, C.Wzs, C.bzs, eps_t, z0_out,
                  C.acc, sh);
  } else {
    if (hasY)
      yhead_phase(blk - 528, t_y, C.g1T, C.Wyl, C.byl, C.Wys, C.bys, C.xT,
                  C.out, C.acc + 1, sh);
  }
}

// ---------------- launch B: phiMLP1(i) | thMLP1(i-2) ----------------
__global__ __launch_bounds__(256) void kB(
    CW C, const float* phiT, const float* z0prev, const float* thT,
    int hasPhiM, int hasThM) {
  __shared__ float red[4 * 8 * 64];  // 8 KB
  const int blk = blockIdx.x;
  if (blk < 256) {
    if (hasPhiM)
      mlp1_phi_phase(blk, phiT, z0prev, C.phi_W1, C.phi_b1, C.h1T,
                     C.pu, C.pw, C.pb, red);
  } else {
    if (hasThM)
      lin8_phase(blk - 256, thT, H, C.th_W1, C.th_b1, C.g1T, 1, red);
  }
}

}  // namespace

extern "C" void kernel_launch(void* const* d_in, const int* in_sizes, int n_in,
                              void* d_out, int out_size, void* d_ws, size_t ws_size,
                              hipStream_t stream) {
  const float* x        = (const float*)d_in[0];
  const float* phi_Wih  = (const float*)d_in[1];
  const float* phi_Whh  = (const float*)d_in[2];
  const float* phi_bih  = (const float*)d_in[3];
  const float* phi_bhh  = (const float*)d_in[4];
  const float* phi_W1   = (const float*)d_in[5];
  const float* phi_b1   = (const float*)d_in[6];
  const float* phi_W2   = (const float*)d_in[7];
  const float* phi_b2   = (const float*)d_in[8];
  const float* zloc_W   = (const float*)d_in[9];
  const float* zloc_b   = (const float*)d_in[10];
  const float* zscale_W = (const float*)d_in[11];
  const float* zscale_b = (const float*)d_in[12];
  const float* pu       = (const float*)d_in[13];
  const float* pw       = (const float*)d_in[14];
  const float* pb       = (const float*)d_in[15];
  const float* th_Wih   = (const float*)d_in[16];
  const float* th_Whh   = (const float*)d_in[17];
  const float* th_bih   = (const float*)d_in[18];
  const float* th_bhh   = (const float*)d_in[19];
  const float* th_W1    = (const float*)d_in[20];
  const float* th_b1    = (const float*)d_in[21];
  const float* th_W2    = (const float*)d_in[22];
  const float* th_b2    = (const float*)d_in[23];
  const float* xloc_W   = (const float*)d_in[24];
  const float* xloc_b   = (const float*)d_in[25];
  const float* xscale_W = (const float*)d_in[26];
  const float* xscale_b = (const float*)d_in[27];

  float* out = (float*)d_out;
  float* ws = (float*)d_ws;

  // workspace layout (floats)
  float* acc   = ws;                        // [0]=kld, [1]=recon
  float* eps_z = ws + 64;                   // LBZ
  float* xT    = eps_z + LBZ;               // LFB
  float* phi0  = xT + LFB;                  // HB
  float* phi1  = phi0 + HB;                 // HB
  float* th0   = phi1 + HB;                 // HB
  float* th1   = th0 + HB;                  // HB
  float* z0a   = th1 + HB;                  // ZB (parity 0)
  float* z0b   = z0a + ZB;                  // ZB (parity 1)
  float* h1T   = z0b + ZB;                  // DB
  float* g1T   = h1T + DB;                  // DB
  float* Wzl   = g1T + DB;                  // Z*D
  float* Wzs   = Wzl + Z * D;               // Z*D
  float* bzl   = Wzs + Z * D;               // 64
  float* bzs   = bzl + 64;                  // 64
  float* Wyl   = bzs + 64;                  // F*D
  float* Wys   = Wyl + F * D;               // F*D
  float* byl   = Wys + F * D;               // 64
  float* bys   = byl + 64;                  // 64

  float* phibuf[2] = {phi0, phi1};
  float* thbuf[2]  = {th0, th1};
  float* z0buf[2]  = {z0a, z0b};

  hipMemsetAsync(acc, 0, 64 * sizeof(float), stream);
  hipMemsetAsync(phi0, 0, (size_t)HB * sizeof(float), stream);  // phi_h(-1)
  hipMemsetAsync(th1, 0, (size_t)HB * sizeof(float), stream);   // th_h(-1)

  // JAX PRNG: key(42)=(0,42); split -> kz, kp
  uint32_t a0, a1, b0, b1;
  threefry2x32_(0u, 42u, 0u, 2u, a0, a1);
  threefry2x32_(0u, 42u, 1u, 3u, b0, b1);
  const uint32_t kz0 = a0, kz1 = b0, kp0 = a1, kp1 = b1;

  k_transpose_x<<<(B * L * F) / 256, 256, 0, stream>>>(x, xT);
  k_noise<<<HALF / 256, 256, 0, stream>>>(eps_z, acc, kz0, kz1, kp0, kp1);

  // Compose linear MLP2 into the z/y heads: Wc = headW @ W2, bc = headW @ b2 + headb.
  k_compose<<<Z, 256, 0, stream>>>(zloc_W, zloc_b, phi_W2, phi_b2, Wzl, bzl);
  k_compose<<<Z, 256, 0, stream>>>(zscale_W, zscale_b, phi_W2, phi_b2, Wzs, bzs);
  k_compose<<<F, 256, 0, stream>>>(xloc_W, xloc_b, th_W2, th_b2, Wyl, byl);
  k_compose<<<F, 256, 0, stream>>>(xscale_W, xscale_b, th_W2, th_b2, Wys, bys);

  CW C;
  C.phi_Wih = phi_Wih; C.phi_Whh = phi_Whh; C.phi_bih = phi_bih; C.phi_bhh = phi_bhh;
  C.phi_W1 = phi_W1; C.phi_b1 = phi_b1;
  C.th_Wih = th_Wih; C.th_Whh = th_Whh; C.th_bih = th_bih; C.th_bhh = th_bhh;
  C.th_W1 = th_W1; C.th_b1 = th_b1;
  C.Wzl = Wzl; C.bzl = bzl; C.Wzs = Wzs; C.bzs = bzs;
  C.Wyl = Wyl; C.byl = byl; C.Wys = Wys; C.bys = bys;
  C.pu = pu; C.pw = pw; C.pb = pb; C.xT = xT;
  C.acc = acc; C.out = out; C.h1T = h1T; C.g1T = g1T;

  // Pipelined schedule, 2 launches per iteration:
  //   A(i): phiGRU(i) | thGRU(i-2) | zhead(i-1) | yhead(i-3)
  //   B(i): phiMLP1(i) [wave3 recomputes flows(z0(i-1))] | thMLP1(i-2)
  for (int i = 0; i <= L + 2; ++i) {
    const int hasPhi = (i < L);
    const int hasTh  = (i >= 2 && i <= L + 1);
    const int hasZ   = (i >= 1 && i <= L);
    const int hasY   = (i >= 3);

    const float* xt     = xT + (size_t)(hasPhi ? i : 0) * F * B;
    const float* phi_c  = phibuf[i & 1];
    float*       phi_n  = phibuf[(i + 1) & 1];
    const float* z0_in  = z0buf[i & 1];          // z0(i-2), parity (i-2)&1 == i&1
    const float* th_c   = thbuf[(i + 1) & 1];    // th_h(i-3), parity (i-3)&1
    float*       th_n   = thbuf[i & 1];          // th_h(i-2), parity (i-2)&1
    float*       z0_out = z0buf[(i + 1) & 1];    // z0(i-1), parity (i-1)&1
    const float* eps_t  = eps_z + (size_t)(hasZ ? (i - 1) : 0) * B * Z;
    const int    t_y    = hasY ? (i - 3) : 0;

    kA<<<568, 256, 0, stream>>>(C, xt, phi_c, phi_n, z0_in, th_c, th_n,
                                z0_out, eps_t, t_y, hasPhi, hasTh, hasZ, hasY);

    const int hasPhiM = (i < L);
    const int hasThM  = (i >= 2 && i <= L + 1);
    if (hasPhiM || hasThM) {
      const float* phiT   = phibuf[(i + 1) & 1];           // phi_h(i)
      const float* z0prev = (i >= 1) ? z0buf[(i + 1) & 1]  // z0(i-1)
                                     : nullptr;            // t==0: z_prev = 0
      const float* thT    = thbuf[i & 1];                  // th_h(i-2)
      kB<<<512, 256, 0, stream>>>(C, phiT, z0prev, thT, hasPhiM, hasThM);
    }
  }

  k_finalize<<<1, 1, 0, stream>>>(acc, out);
}